// Round 3
// baseline (473.466 us; speedup 1.0000x reference)
//
#include <hip/hip_runtime.h>
#include <hip/hip_fp16.h>

typedef _Float16 f16x8 __attribute__((ext_vector_type(8)));
typedef _Float16 f16x4 __attribute__((ext_vector_type(4)));
typedef _Float16 f16x2 __attribute__((ext_vector_type(2)));
typedef float    f32x16 __attribute__((ext_vector_type(16)));
typedef float    f32x4 __attribute__((ext_vector_type(4)));

struct LayerPtrs {
  const float* w[8];
  const float* b[8];
};

// Weight fragments in d_ws, A-operand layout for mfma_f32_32x32x16_f16:
//   m = mtile*32 + (lane&31), k = kc*16 + (lane>>5)*8 + j ; value = W[k][m]
// index = WOFF[l] + (kc*8 + mtile)*64 + lane, element j.
__global__ void prep_weights(LayerPtrs P, f16x8* __restrict__ wf) {
  int gid = blockIdx.x * 256 + threadIdx.x;
  if (gid >= 60416) return;
  const int OFF[9] = {0,1536,9728,17920,26112,35840,44032,52224,60416};
  int l = 0;
  while (gid >= OFF[l+1]) ++l;
  int f = gid - OFF[l];
  int lane = f & 63;
  int t = f >> 6;
  int mtile = t & 7;
  int kc = t >> 3;
  int col = mtile * 32 + (lane & 31);
  int kb  = (lane >> 5) * 8;
  const float* w = P.w[l];
  f16x8 v;
#pragma unroll
  for (int j = 0; j < 8; ++j) {
    float x = 0.f;
    if (l == 4) {
      if (kc < 3) {
        int k = kc * 16 + kb + j;
        if (k < 39) x = w[k * 256 + col];
      } else {
        int k = (kc - 3) * 16 + kb + j;
        x = w[(39 + k) * 256 + col];
      }
    } else if (l == 0) {
      int k = kc * 16 + kb + j;
      if (k < 39) x = w[k * 256 + col];
    } else {
      int k = kc * 16 + kb + j;
      x = w[k * 256 + col];
    }
    v[j] = (_Float16)x;
  }
  wf[gid] = v;
}

#define MFMA __builtin_amdgcn_mfma_f32_32x32x16_f16

// Wave = 128 hidden (4 mt) x 64 points (2 nt): 8 MFMA per kc.
// Rationale (round-2 post-mortem): LDS B-read traffic per MFMA = 1KB/mt;
// mt=2 saturated the ~85 B/cyc/CU ds_read_b128 ceiling and capped MfmaUtil
// at ~50%. mt=4 halves B traffic. A (weights) from L2, depth-2 prefetch;
// B (activations, LDS) depth-1. Nothing live across barriers (round-1 lesson).
// Activation rows XOR-swizzled: physical byte = logical ^ xr, xr=(p0&7)<<4.
// FIRST: kc0 uses a zero C operand (bias is added in the epilogue).
template<int NKC, bool FIRST, int RSTRIDE>
__device__ __forceinline__ void mm(const f16x8* __restrict__ wb,
                                   const char* __restrict__ r0,
                                   int col0, int xr,
                                   f32x16 acc[4][2]) {
  f16x8 a0 = wb[0], a1 = wb[64], a2 = wb[128], a3 = wb[192];
  f16x8 b0, b1, b2, b3;
  if (NKC > 1) { b0 = wb[512]; b1 = wb[576]; b2 = wb[640]; b3 = wb[704]; }
  int off0 = col0 ^ xr;
  f16x8 v0 = *(const f16x8*)(r0 + off0);
  f16x8 v1 = *(const f16x8*)(r0 + RSTRIDE + off0);
#pragma unroll
  for (int kc = 0; kc < NKC; ++kc) {
    f16x8 na0, na1, na2, na3, nv0, nv1;
    if (kc + 2 < NKC) {
      na0 = wb[(kc + 2) * 512];
      na1 = wb[(kc + 2) * 512 + 64];
      na2 = wb[(kc + 2) * 512 + 128];
      na3 = wb[(kc + 2) * 512 + 192];
    }
    if (kc + 1 < NKC) {
      int off = (col0 + 32 * (kc + 1)) ^ xr;
      nv0 = *(const f16x8*)(r0 + off);
      nv1 = *(const f16x8*)(r0 + RSTRIDE + off);
    }
    if (FIRST && kc == 0) {
      const f32x16 z = {};
      acc[0][0] = MFMA(a0, v0, z, 0, 0, 0);
      acc[0][1] = MFMA(a0, v1, z, 0, 0, 0);
      acc[1][0] = MFMA(a1, v0, z, 0, 0, 0);
      acc[1][1] = MFMA(a1, v1, z, 0, 0, 0);
      acc[2][0] = MFMA(a2, v0, z, 0, 0, 0);
      acc[2][1] = MFMA(a2, v1, z, 0, 0, 0);
      acc[3][0] = MFMA(a3, v0, z, 0, 0, 0);
      acc[3][1] = MFMA(a3, v1, z, 0, 0, 0);
    } else {
      acc[0][0] = MFMA(a0, v0, acc[0][0], 0, 0, 0);
      acc[0][1] = MFMA(a0, v1, acc[0][1], 0, 0, 0);
      acc[1][0] = MFMA(a1, v0, acc[1][0], 0, 0, 0);
      acc[1][1] = MFMA(a1, v1, acc[1][1], 0, 0, 0);
      acc[2][0] = MFMA(a2, v0, acc[2][0], 0, 0, 0);
      acc[2][1] = MFMA(a2, v1, acc[2][1], 0, 0, 0);
      acc[3][0] = MFMA(a3, v0, acc[3][0], 0, 0, 0);
      acc[3][1] = MFMA(a3, v1, acc[3][1], 0, 0, 0);
    }
    a0 = b0; a1 = b1; a2 = b2; a3 = b3;
    b0 = na0; b1 = na1; b2 = na2; b3 = na3;
    v0 = nv0; v1 = nv1;
  }
}

__device__ __forceinline__ f16x4 relu_cvt4(float a0, float a1, float a2, float a3) {
  f16x2 lo = __builtin_bit_cast(f16x2, __builtin_amdgcn_cvt_pkrtz(a0, a1));
  f16x2 hi = __builtin_bit_cast(f16x2, __builtin_amdgcn_cvt_pkrtz(a2, a3));
  union { f16x4 v; f16x2 h[2]; } u;
  u.h[0] = lo; u.h[1] = hi;
  f16x4 z = {};
  return __builtin_elementwise_max(u.v, z);
}

// C/D 32x32: col(point) = lane&31, row(hidden) = (reg&3) + 8*(reg>>2) + 4*(lane>>5)
// Epilogue adds bias (acc + b) before relu, then f16x4 store, XOR-swizzled.
__device__ __forceinline__ void store_epi(f32x16 acc[4][2],
                                          const float* __restrict__ bias,
                                          int wg_h, int wg_p, int p0, int h,
                                          int xr, _Float16* __restrict__ Hs) {
  char* base = (char*)Hs + (wg_p * 64 + p0) * 512;
#pragma unroll
  for (int mt = 0; mt < 4; ++mt) {
#pragma unroll
    for (int g = 0; g < 4; ++g) {
      f32x4 q = *(const f32x4*)&bias[wg_h * 128 + mt * 32 + 8 * g + 4 * h];
      int bc = (256 * wg_h + 64 * mt + 16 * g + 8 * h) ^ xr;
#pragma unroll
      for (int nt = 0; nt < 2; ++nt) {
        f16x4 o = relu_cvt4(acc[mt][nt][4 * g + 0] + q[0],
                            acc[mt][nt][4 * g + 1] + q[1],
                            acc[mt][nt][4 * g + 2] + q[2],
                            acc[mt][nt][4 * g + 3] + q[3]);
        *(f16x4*)(base + nt * 32 * 512 + bc) = o;
      }
    }
  }
}

__device__ __forceinline__ void emb_channel(char* __restrict__ Erow, int xp,
                                            int c, float x) {
  _Float16 sv[6], cv[6];
  float fr = 1.f;
#pragma unroll
  for (int k = 0; k < 6; ++k) {
    float e = x * fr;
    sv[k] = (_Float16)__sinf(e);
    cv[k] = (_Float16)__cosf(e);
    fr *= 2.f;
  }
#pragma unroll
  for (int k = 0; k < 6; k += 2) {
    f16x2 s2 = {sv[k], sv[k + 1]};
    f16x2 c2 = {cv[k], cv[k + 1]};
    *(f16x2*)(Erow + ((2 * (6 * c + k)) ^ xp)) = s2;
    *(f16x2*)(Erow + ((2 * (18 + 6 * c + k)) ^ xp)) = c2;
  }
  *(_Float16*)(Erow + ((2 * (36 + c)) ^ xp)) = (_Float16)x;
}

// 256 threads = 4 waves: wg_h = wave>>1 (hidden 128-slice), wg_p = wave&1
// (points 64-slice). 128 points/block. LDS: H 128x256 f16 (64KB, swizzled)
// + E 128x64 f16 (16KB) = 81920 B -> 2 blocks/CU, 8 waves/CU (2/SIMD).
__global__ __launch_bounds__(256, 2)
void mlp_fused(const float* __restrict__ points,
               LayerPtrs P,
               const f16x8* __restrict__ wf,
               const float* __restrict__ wsdf,
               const float* __restrict__ bsdf,
               float* __restrict__ out) {
  __shared__ __align__(16) _Float16 Hs[128 * 256];   // 65536 B
  __shared__ __align__(16) _Float16 Es[128 * 64];    // 16384 B
  const int tid = threadIdx.x;
  const int blk = blockIdx.x;

  const int lane = tid & 63;
  const int w    = tid >> 6;
  const int wg_h = w >> 1;
  const int wg_p = w & 1;
  const int p0   = lane & 31;
  const int h    = lane >> 5;
  const int xr   = (p0 & 7) << 4;
  const int col0 = 16 * h;

  // frag(l, kc, mt) = wb[WOFF[l] + kc*512 + mt*64]; wave owns mtiles 4wg_h..+3
  const f16x8* wb = wf + wg_h * 256 + lane;

  // ---- embedding: 2 threads/point. part0 -> ch0,ch1; part1 -> ch2 + pad.
  // E logical cols: [sin(18) | cos(18) | xyz(3) | zeros 39..47]; row = point.
  {
    int p = tid & 127, part = tid >> 7;
    char* Erow = (char*)Es + p * 128;
    int xp = (p & 7) << 4;
    const float* pp = &points[(blk * 128 + p) * 3];
    if (part == 0) {
      emb_channel(Erow, xp, 0, pp[0]);
      emb_channel(Erow, xp, 1, pp[1]);
    } else {
      emb_channel(Erow, xp, 2, pp[2]);
      f16x4 z4 = {};
      *(_Float16*)(Erow + (78 ^ xp)) = (_Float16)0.f;   // col 39
      *(f16x4*)(Erow + (80 ^ xp)) = z4;                 // cols 40..43
      *(f16x4*)(Erow + (88 ^ xp)) = z4;                 // cols 44..47
    }
  }
  __syncthreads();

  const char* hR = (const char*)Hs + (wg_p * 64 + p0) * 512;
  const char* eR = (const char*)Es + (wg_p * 64 + p0) * 128;

  f32x16 acc[4][2];

  // L0: read E, write H (disjoint -> no barrier between mm and store)
  mm<3, true, 4096>(wb, eR, col0, xr, acc);
  store_epi(acc, P.b[0], wg_h, wg_p, p0, h, xr, Hs);
  __syncthreads();

  const int WOFF[8] = {0, 1536, 9728, 17920, 26112, 35840, 44032, 52224};

  // L1..L3: in-place H
#pragma unroll
  for (int l = 1; l < 4; ++l) {
    mm<16, true, 16384>(wb + WOFF[l], hR, col0, xr, acc);
    __syncthreads();
    store_epi(acc, P.b[l], wg_h, wg_p, p0, h, xr, Hs);
    __syncthreads();
  }

  // L4: concat input = E (3 kc, zero-C) + H (16 kc, accumulate)
  {
    mm<3, true, 4096>(wb + 26112, eR, col0, xr, acc);
    mm<16, false, 16384>(wb + 27648, hR, col0, xr, acc);
    __syncthreads();
    store_epi(acc, P.b[4], wg_h, wg_p, p0, h, xr, Hs);
    __syncthreads();
  }

  // L5..L6
#pragma unroll
  for (int l = 5; l < 7; ++l) {
    mm<16, true, 16384>(wb + WOFF[l], hR, col0, xr, acc);
    __syncthreads();
    store_epi(acc, P.b[l], wg_h, wg_p, p0, h, xr, Hs);
    __syncthreads();
  }

  // L7 + SDF head: out[p] = sum_h relu(x7 + b7)[p][h] * wsdf[h] + bsdf
  mm<16, true, 16384>(wb + 52224, hR, col0, xr, acc);
  {
    float part0 = 0.f, part1 = 0.f;
    const float* b7 = P.b[7];
#pragma unroll
    for (int mt = 0; mt < 4; ++mt) {
#pragma unroll
      for (int g = 0; g < 4; ++g) {
        int idx = wg_h * 128 + mt * 32 + 8 * g + 4 * h;
        f32x4 qb = *(const f32x4*)&b7[idx];
        f32x4 qw = *(const f32x4*)&wsdf[idx];
#pragma unroll
        for (int r = 0; r < 4; ++r) {
          part0 += fmaxf(acc[mt][0][4 * g + r] + qb[r], 0.f) * qw[r];
          part1 += fmaxf(acc[mt][1][4 * g + r] + qb[r], 0.f) * qw[r];
        }
      }
    }
    // E space dead since L4 (block-wide barriers since) -> partial buffer
    // PB[4][128] floats (2 KB). PB writes touch only Es; L7 reads only Hs.
    float* PB = (float*)Es;
    PB[(wg_h * 2 + h) * 128 + wg_p * 64 + p0]      = part0;
    PB[(wg_h * 2 + h) * 128 + wg_p * 64 + 32 + p0] = part1;
    __syncthreads();
    if (tid < 128) {
      float s = bsdf[0];
#pragma unroll
      for (int j = 0; j < 4; ++j) s += PB[j * 128 + tid];
      out[blk * 128 + tid] = s;
    }
  }
}

extern "C" void kernel_launch(void* const* d_in, const int* in_sizes, int n_in,
                              void* d_out, int out_size, void* d_ws, size_t ws_size,
                              hipStream_t stream) {
  const float* points = (const float*)d_in[0];
  LayerPtrs P;
  for (int i = 0; i < 8; ++i) {
    P.w[i] = (const float*)d_in[1 + 2 * i];
    P.b[i] = (const float*)d_in[2 + 2 * i];
  }
  const float* wsdf = (const float*)d_in[17];
  const float* bsdf = (const float*)d_in[18];
  f16x8* wf = (f16x8*)d_ws;   // needs 966656 B

  int N = in_sizes[0] / 3;    // 262144
  prep_weights<<<236, 256, 0, stream>>>(P, wf);
  mlp_fused<<<N / 128, 256, 0, stream>>>(points, P, wf, wsdf, bsdf, (float*)d_out);
}

// Round 5
// 322.418 us; speedup vs baseline: 1.4685x; 1.4685x over previous
//
#include <hip/hip_runtime.h>
#include <hip/hip_fp16.h>

typedef _Float16 f16x8 __attribute__((ext_vector_type(8)));
typedef _Float16 f16x4 __attribute__((ext_vector_type(4)));
typedef _Float16 f16x2 __attribute__((ext_vector_type(2)));
typedef float    f32x16 __attribute__((ext_vector_type(16)));
typedef float    f32x4 __attribute__((ext_vector_type(4)));

#define SH 264   // H row stride (f16): 264*2=528 B; 528 mod 128 = 16 -> banks spread
#define SE 56    // E row stride (f16): 112 B; 112 mod 128 = 112 -> banks spread

struct LayerPtrs {
  const float* w[8];
  const float* b[8];
};

// Weight fragments in d_ws, A-operand layout for mfma_f32_32x32x16_f16:
//   m = mtile*32 + (lane&31), k = kc*16 + (lane>>5)*8 + j ; value = W[k][m]
// index = WOFF[l] + (kc*8 + mtile)*64 + lane, element j.
__global__ void prep_weights(LayerPtrs P, f16x8* __restrict__ wf) {
  int gid = blockIdx.x * 256 + threadIdx.x;
  if (gid >= 60416) return;
  const int OFF[9] = {0,1536,9728,17920,26112,35840,44032,52224,60416};
  int l = 0;
  while (gid >= OFF[l+1]) ++l;
  int f = gid - OFF[l];
  int lane = f & 63;
  int t = f >> 6;
  int mtile = t & 7;
  int kc = t >> 3;
  int col = mtile * 32 + (lane & 31);
  int kb  = (lane >> 5) * 8;
  const float* w = P.w[l];
  f16x8 v;
#pragma unroll
  for (int j = 0; j < 8; ++j) {
    float x = 0.f;
    if (l == 4) {
      if (kc < 3) {
        int k = kc * 16 + kb + j;
        if (k < 39) x = w[k * 256 + col];
      } else {
        int k = (kc - 3) * 16 + kb + j;
        x = w[(39 + k) * 256 + col];
      }
    } else if (l == 0) {
      int k = kc * 16 + kb + j;
      if (k < 39) x = w[k * 256 + col];
    } else {
      int k = kc * 16 + kb + j;
      x = w[k * 256 + col];
    }
    v[j] = (_Float16)x;
  }
  wf[gid] = v;
}

#define MFMA __builtin_amdgcn_mfma_f32_32x32x16_f16

__device__ __forceinline__ void mfma8(f16x8 a0, f16x8 a1, f16x8 a2, f16x8 a3,
                                      f16x8 v0, f16x8 v1, f32x16 acc[4][2]) {
  acc[0][0] = MFMA(a0, v0, acc[0][0], 0, 0, 0);
  acc[0][1] = MFMA(a0, v1, acc[0][1], 0, 0, 0);
  acc[1][0] = MFMA(a1, v0, acc[1][0], 0, 0, 0);
  acc[1][1] = MFMA(a1, v1, acc[1][1], 0, 0, 0);
  acc[2][0] = MFMA(a2, v0, acc[2][0], 0, 0, 0);
  acc[2][1] = MFMA(a2, v1, acc[2][1], 0, 0, 0);
  acc[3][0] = MFMA(a3, v0, acc[3][0], 0, 0, 0);
  acc[3][1] = MFMA(a3, v1, acc[3][1], 0, 0, 0);
}

__device__ __forceinline__ void mfma8_z(f16x8 a0, f16x8 a1, f16x8 a2, f16x8 a3,
                                        f16x8 v0, f16x8 v1, f32x16 acc[4][2]) {
  const f32x16 z = {};
  acc[0][0] = MFMA(a0, v0, z, 0, 0, 0);
  acc[0][1] = MFMA(a0, v1, z, 0, 0, 0);
  acc[1][0] = MFMA(a1, v0, z, 0, 0, 0);
  acc[1][1] = MFMA(a1, v1, z, 0, 0, 0);
  acc[2][0] = MFMA(a2, v0, z, 0, 0, 0);
  acc[2][1] = MFMA(a2, v1, z, 0, 0, 0);
  acc[3][0] = MFMA(a3, v0, z, 0, 0, 0);
  acc[3][1] = MFMA(a3, v1, z, 0, 0, 0);
}

// Wave = 128 hidden (4 mt) x 64 points (2 nt): 8 independent MFMA per kc.
// mt=4 halves LDS B-read bytes per MFMA vs mt=2 (256 B vs 512 B).
// A (weights, L2) depth-1 prefetch; B (LDS) depth-1. kc loop is a RUNTIME
// loop with #pragma unroll 2 + running pointers: bounds the scheduler's
// load hoisting (round-3 lesson: full unroll at a loose reg budget ->
// liveness explosion -> 93 MB scratch spill).
// First/last kc peeled; FIRST uses zero-C on kc0 (bias added in epilogue).
template<int NKC, bool FIRST, int RSTRIDE>
__device__ __forceinline__ void mm(const f16x8* __restrict__ wb,
                                   const char* __restrict__ r0,
                                   int hoff, f32x16 acc[4][2]) {
  f16x8 a0 = wb[0], a1 = wb[64], a2 = wb[128], a3 = wb[192];
  const char* rp = r0 + hoff;
  f16x8 v0 = *(const f16x8*)(rp);
  f16x8 v1 = *(const f16x8*)(rp + RSTRIDE);
  // kc = 0 (peeled: FIRST variant + prefetch kc=1)
  {
    const f16x8* wn = wb + 512;
    f16x8 na0 = wn[0], na1 = wn[64], na2 = wn[128], na3 = wn[192];
    f16x8 nv0 = *(const f16x8*)(rp + 32);
    f16x8 nv1 = *(const f16x8*)(rp + RSTRIDE + 32);
    if (FIRST) mfma8_z(a0, a1, a2, a3, v0, v1, acc);
    else       mfma8(a0, a1, a2, a3, v0, v1, acc);
    a0 = na0; a1 = na1; a2 = na2; a3 = na3; v0 = nv0; v1 = nv1;
  }
  const f16x8* wp = wb + 1024;   // A frags for kc+1 inside the loop
  rp += 64;                      // B row bytes for kc+1 inside the loop
#pragma unroll 2
  for (int kc = 1; kc < NKC - 1; ++kc) {
    f16x8 na0 = wp[0], na1 = wp[64], na2 = wp[128], na3 = wp[192];
    f16x8 nv0 = *(const f16x8*)(rp);
    f16x8 nv1 = *(const f16x8*)(rp + RSTRIDE);
    mfma8(a0, a1, a2, a3, v0, v1, acc);
    a0 = na0; a1 = na1; a2 = na2; a3 = na3; v0 = nv0; v1 = nv1;
    wp += 512; rp += 32;
  }
  mfma8(a0, a1, a2, a3, v0, v1, acc);   // kc = NKC-1
}

__device__ __forceinline__ f16x4 relu_cvt4(float a0, float a1, float a2, float a3) {
  f16x2 lo = __builtin_bit_cast(f16x2, __builtin_amdgcn_cvt_pkrtz(a0, a1));
  f16x2 hi = __builtin_bit_cast(f16x2, __builtin_amdgcn_cvt_pkrtz(a2, a3));
  union { f16x4 v; f16x2 h[2]; } u;
  u.h[0] = lo; u.h[1] = hi;
  f16x4 z = {};
  return __builtin_elementwise_max(u.v, z);
}

// C/D 32x32: col(point) = lane&31, row(hidden) = (reg&3) + 8*(reg>>2) + 4*(lane>>5)
// Epilogue adds bias (acc + b) before relu, then f16x4 store.
__device__ __forceinline__ void store_epi(f32x16 acc[4][2],
                                          const float* __restrict__ bias,
                                          int wg_h, int wg_p, int p0, int h,
                                          _Float16* __restrict__ Hs) {
  char* base = (char*)Hs + (wg_p * 64 + p0) * (SH * 2);
#pragma unroll
  for (int mt = 0; mt < 4; ++mt) {
#pragma unroll
    for (int g = 0; g < 4; ++g) {
      f32x4 q = *(const f32x4*)&bias[wg_h * 128 + mt * 32 + 8 * g + 4 * h];
      int bc = 256 * wg_h + 64 * mt + 16 * g + 8 * h;   // byte col = 2*hidden
#pragma unroll
      for (int nt = 0; nt < 2; ++nt) {
        f16x4 o = relu_cvt4(acc[mt][nt][4 * g + 0] + q[0],
                            acc[mt][nt][4 * g + 1] + q[1],
                            acc[mt][nt][4 * g + 2] + q[2],
                            acc[mt][nt][4 * g + 3] + q[3]);
        *(f16x4*)(base + nt * 32 * (SH * 2) + bc) = o;
      }
    }
  }
}

__device__ __forceinline__ void emb_channel(_Float16* __restrict__ Erow,
                                            int c, float x) {
  _Float16 sv[6], cv[6];
  float fr = 1.f;
#pragma unroll
  for (int k = 0; k < 6; ++k) {
    float e = x * fr;
    sv[k] = (_Float16)__sinf(e);
    cv[k] = (_Float16)__cosf(e);
    fr *= 2.f;
  }
#pragma unroll
  for (int k = 0; k < 6; k += 2) {
    f16x2 s2 = {sv[k], sv[k + 1]};
    f16x2 c2 = {cv[k], cv[k + 1]};
    *(f16x2*)&Erow[6 * c + k]      = s2;
    *(f16x2*)&Erow[18 + 6 * c + k] = c2;
  }
  Erow[36 + c] = (_Float16)x;
}

// 256 threads = 4 waves: wg_h = wave>>1 (hidden 128-slice), wg_p = wave&1
// (points 64-slice). 128 points/block. LDS: H 128xSH f16 (67584 B) +
// E 128xSE f16 (14336 B) = 81920 B -> 2 blocks/CU, 8 waves/CU (2/SIMD).
__global__ __launch_bounds__(256, 2)
void mlp_fused(const float* __restrict__ points,
               LayerPtrs P,
               const f16x8* __restrict__ wf,
               const float* __restrict__ wsdf,
               const float* __restrict__ bsdf,
               float* __restrict__ out) {
  __shared__ __align__(16) _Float16 Hs[128 * SH];   // 67584 B
  __shared__ __align__(16) _Float16 Es[128 * SE];   // 14336 B
  const int tid = threadIdx.x;
  const int blk = blockIdx.x;

  const int lane = tid & 63;
  const int w    = tid >> 6;
  const int wg_h = w >> 1;
  const int wg_p = w & 1;
  const int p0   = lane & 31;
  const int h    = lane >> 5;
  const int hoff = 16 * h;   // byte offset of this lane's k-half within a row col

  // frag(l, kc, mt) = wb[WOFF[l] + kc*512 + mt*64]; wave owns mtiles 4wg_h..+3
  const f16x8* wb = wf + wg_h * 256 + lane;

  // ---- embedding: 2 threads/point. part0 -> ch0,ch1; part1 -> ch2 + pad.
  // E cols: [sin(18) | cos(18) | xyz(3) | zeros 39..55]; row = point.
  {
    int p = tid & 127, part = tid >> 7;
    _Float16* Erow = &Es[p * SE];
    const float* pp = &points[(blk * 128 + p) * 3];
    if (part == 0) {
      emb_channel(Erow, 0, pp[0]);
      emb_channel(Erow, 1, pp[1]);
    } else {
      emb_channel(Erow, 2, pp[2]);
      Erow[39] = (_Float16)0.f;
      f16x4 z4 = {};
      *(f16x4*)&Erow[40] = z4;
      *(f16x4*)&Erow[44] = z4;
      *(f16x4*)&Erow[48] = z4;
      *(f16x4*)&Erow[52] = z4;
    }
  }
  __syncthreads();

  const char* hR = (const char*)Hs + (wg_p * 64 + p0) * (SH * 2);
  const char* eR = (const char*)Es + (wg_p * 64 + p0) * (SE * 2);

  f32x16 acc[4][2];

  // L0: read E, write H (disjoint -> no barrier between mm and store)
  mm<3, true, 32 * SE * 2>(wb, eR, hoff, acc);
  store_epi(acc, P.b[0], wg_h, wg_p, p0, h, Hs);
  __syncthreads();

  const int WOFF[8] = {0, 1536, 9728, 17920, 26112, 35840, 44032, 52224};

  // L1..L3: in-place H
#pragma unroll
  for (int l = 1; l < 4; ++l) {
    mm<16, true, 32 * SH * 2>(wb + WOFF[l], hR, hoff, acc);
    __syncthreads();
    store_epi(acc, P.b[l], wg_h, wg_p, p0, h, Hs);
    __syncthreads();
  }

  // L4: concat input = E (3 kc, zero-C) + H (16 kc, accumulate)
  {
    mm<3, true, 32 * SE * 2>(wb + 26112, eR, hoff, acc);
    mm<16, false, 32 * SH * 2>(wb + 27648, hR, hoff, acc);
    __syncthreads();
    store_epi(acc, P.b[4], wg_h, wg_p, p0, h, Hs);
    __syncthreads();
  }

  // L5..L6
#pragma unroll
  for (int l = 5; l < 7; ++l) {
    mm<16, true, 32 * SH * 2>(wb + WOFF[l], hR, hoff, acc);
    __syncthreads();
    store_epi(acc, P.b[l], wg_h, wg_p, p0, h, Hs);
    __syncthreads();
  }

  // L7 + SDF head: out[p] = sum_h relu(x7 + b7)[p][h] * wsdf[h] + bsdf
  mm<16, true, 32 * SH * 2>(wb + 52224, hR, hoff, acc);
  {
    float part0 = 0.f, part1 = 0.f;
    const float* b7 = P.b[7];
#pragma unroll
    for (int mt = 0; mt < 4; ++mt) {
#pragma unroll
      for (int g = 0; g < 4; ++g) {
        int idx = wg_h * 128 + mt * 32 + 8 * g + 4 * h;
        f32x4 qb = *(const f32x4*)&b7[idx];
        f32x4 qw = *(const f32x4*)&wsdf[idx];
#pragma unroll
        for (int r = 0; r < 4; ++r) {
          part0 += fmaxf(acc[mt][0][4 * g + r] + qb[r], 0.f) * qw[r];
          part1 += fmaxf(acc[mt][1][4 * g + r] + qb[r], 0.f) * qw[r];
        }
      }
    }
    // E space dead since L4 (block-wide barriers since) -> partial buffer
    // PB[4][128] floats (2 KB). PB writes touch only Es; L7 reads only Hs.
    float* PB = (float*)Es;
    PB[(wg_h * 2 + h) * 128 + wg_p * 64 + p0]      = part0;
    PB[(wg_h * 2 + h) * 128 + wg_p * 64 + 32 + p0] = part1;
    __syncthreads();
    if (tid < 128) {
      float s = bsdf[0];
#pragma unroll
      for (int j = 0; j < 4; ++j) s += PB[j * 128 + tid];
      out[blk * 128 + tid] = s;
    }
  }
}

extern "C" void kernel_launch(void* const* d_in, const int* in_sizes, int n_in,
                              void* d_out, int out_size, void* d_ws, size_t ws_size,
                              hipStream_t stream) {
  const float* points = (const float*)d_in[0];
  LayerPtrs P;
  for (int i = 0; i < 8; ++i) {
    P.w[i] = (const float*)d_in[1 + 2 * i];
    P.b[i] = (const float*)d_in[2 + 2 * i];
  }
  const float* wsdf = (const float*)d_in[17];
  const float* bsdf = (const float*)d_in[18];
  f16x8* wf = (f16x8*)d_ws;   // needs 966656 B

  int N = in_sizes[0] / 3;    // 262144
  prep_weights<<<236, 256, 0, stream>>>(P, wf);
  mlp_fused<<<N / 128, 256, 0, stream>>>(points, P, wf, wsdf, bsdf, (float*)d_out);
}

// Round 6
// 299.615 us; speedup vs baseline: 1.5802x; 1.0761x over previous
//
#include <hip/hip_runtime.h>
#include <hip/hip_fp16.h>

typedef _Float16 f16x8 __attribute__((ext_vector_type(8)));
typedef _Float16 f16x4 __attribute__((ext_vector_type(4)));
typedef _Float16 f16x2 __attribute__((ext_vector_type(2)));
typedef float    f32x16 __attribute__((ext_vector_type(16)));
typedef float    f32x4 __attribute__((ext_vector_type(4)));

#define SH 264   // H row stride (f16): 528 B; 528 mod 128 = 16 -> banks spread
#define SE 56    // E row stride (f16): 112 B; 112 mod 128 = 112 -> banks spread

struct LayerPtrs {
  const float* w[8];
  const float* b[8];
};

// Weight fragments in d_ws, A-operand layout for mfma_f32_32x32x16_f16:
//   m = mtile*32 + (lane&31), k = kc*16 + (lane>>5)*8 + j ; value = W[k][m]
// index = WOFF[l] + (kc*8 + mtile)*64 + lane, element j.
__global__ void prep_weights(LayerPtrs P, f16x8* __restrict__ wf) {
  int gid = blockIdx.x * 256 + threadIdx.x;
  if (gid >= 60416) return;
  const int OFF[9] = {0,1536,9728,17920,26112,35840,44032,52224,60416};
  int l = 0;
  while (gid >= OFF[l+1]) ++l;
  int f = gid - OFF[l];
  int lane = f & 63;
  int t = f >> 6;
  int mtile = t & 7;
  int kc = t >> 3;
  int col = mtile * 32 + (lane & 31);
  int kb  = (lane >> 5) * 8;
  const float* w = P.w[l];
  f16x8 v;
#pragma unroll
  for (int j = 0; j < 8; ++j) {
    float x = 0.f;
    if (l == 4) {
      if (kc < 3) {
        int k = kc * 16 + kb + j;
        if (k < 39) x = w[k * 256 + col];
      } else {
        int k = (kc - 3) * 16 + kb + j;
        x = w[(39 + k) * 256 + col];
      }
    } else if (l == 0) {
      int k = kc * 16 + kb + j;
      if (k < 39) x = w[k * 256 + col];
    } else {
      int k = kc * 16 + kb + j;
      x = w[k * 256 + col];
    }
    v[j] = (_Float16)x;
  }
  wf[gid] = v;
}

#define MFMA __builtin_amdgcn_mfma_f32_32x32x16_f16

__device__ __forceinline__ void mfma8(f16x8 a0, f16x8 a1,
                                      f16x8 v0, f16x8 v1, f16x8 v2, f16x8 v3,
                                      f32x16 acc[2][4]) {
  acc[0][0] = MFMA(a0, v0, acc[0][0], 0, 0, 0);
  acc[0][1] = MFMA(a0, v1, acc[0][1], 0, 0, 0);
  acc[0][2] = MFMA(a0, v2, acc[0][2], 0, 0, 0);
  acc[0][3] = MFMA(a0, v3, acc[0][3], 0, 0, 0);
  acc[1][0] = MFMA(a1, v0, acc[1][0], 0, 0, 0);
  acc[1][1] = MFMA(a1, v1, acc[1][1], 0, 0, 0);
  acc[1][2] = MFMA(a1, v2, acc[1][2], 0, 0, 0);
  acc[1][3] = MFMA(a1, v3, acc[1][3], 0, 0, 0);
}

__device__ __forceinline__ void mfma8_z(f16x8 a0, f16x8 a1,
                                        f16x8 v0, f16x8 v1, f16x8 v2, f16x8 v3,
                                        f32x16 acc[2][4]) {
  const f32x16 z = {};
  acc[0][0] = MFMA(a0, v0, z, 0, 0, 0);
  acc[0][1] = MFMA(a0, v1, z, 0, 0, 0);
  acc[0][2] = MFMA(a0, v2, z, 0, 0, 0);
  acc[0][3] = MFMA(a0, v3, z, 0, 0, 0);
  acc[1][0] = MFMA(a1, v0, z, 0, 0, 0);
  acc[1][1] = MFMA(a1, v1, z, 0, 0, 0);
  acc[1][2] = MFMA(a1, v2, z, 0, 0, 0);
  acc[1][3] = MFMA(a1, v3, z, 0, 0, 0);
}

// Wave = 64 hidden (2 mt) x 128 points (4 nt): 8 MFMA per kc, per-wave
// DISTINCT weight slice (1x L2 A-traffic). Round-6 change: A prefetch
// DISTANCE-2 (3 live stages) -- rounds 0/2/5 all sat at ~50% MfmaUtil with
// distance-1 cover (~128 cyc) vs ~225 cyc L2 hit latency. V (LDS) stays
// distance-1. Runtime kc loop + unroll 2 bounds scheduler hoisting
// (round-3 lesson). Nothing live across barriers (round-1 lesson).
// FIRST: kc0 uses zero C operand (bias added in epilogue). NKC >= 3.
template<int NKC, bool FIRST, int RSTRIDE>
__device__ __forceinline__ void mm(const f16x8* __restrict__ wb,
                                   const char* __restrict__ r0,
                                   f32x16 acc[2][4]) {
  f16x8 a00 = wb[0],   a01 = wb[64];    // A(0)
  f16x8 a10 = wb[512], a11 = wb[576];   // A(1)
  f16x8 v00 = *(const f16x8*)(r0);
  f16x8 v01 = *(const f16x8*)(r0 + RSTRIDE);
  f16x8 v02 = *(const f16x8*)(r0 + 2 * RSTRIDE);
  f16x8 v03 = *(const f16x8*)(r0 + 3 * RSTRIDE);
  // kc = 0 (peeled): load A(2), V(1)
  {
    f16x8 na0 = wb[1024], na1 = wb[1088];
    f16x8 nv0 = *(const f16x8*)(r0 + 32);
    f16x8 nv1 = *(const f16x8*)(r0 + RSTRIDE + 32);
    f16x8 nv2 = *(const f16x8*)(r0 + 2 * RSTRIDE + 32);
    f16x8 nv3 = *(const f16x8*)(r0 + 3 * RSTRIDE + 32);
    if (FIRST) mfma8_z(a00, a01, v00, v01, v02, v03, acc);
    else       mfma8 (a00, a01, v00, v01, v02, v03, acc);
    a00 = a10; a01 = a11; a10 = na0; a11 = na1;
    v00 = nv0; v01 = nv1; v02 = nv2; v03 = nv3;
  }
  const f16x8* wp = wb + 1536;   // A(kc+2) source at kc=1
  const char* rp  = r0 + 64;     // V(kc+1) source at kc=1
#pragma unroll 2
  for (int kc = 1; kc <= NKC - 3; ++kc) {
    f16x8 na0 = wp[0], na1 = wp[64];
    f16x8 nv0 = *(const f16x8*)(rp);
    f16x8 nv1 = *(const f16x8*)(rp + RSTRIDE);
    f16x8 nv2 = *(const f16x8*)(rp + 2 * RSTRIDE);
    f16x8 nv3 = *(const f16x8*)(rp + 3 * RSTRIDE);
    mfma8(a00, a01, v00, v01, v02, v03, acc);
    a00 = a10; a01 = a11; a10 = na0; a11 = na1;
    v00 = nv0; v01 = nv1; v02 = nv2; v03 = nv3;
    wp += 512; rp += 32;
  }
  // kc = NKC-2: load V(NKC-1) only (A all fetched; rp == r0 + 32*(NKC-1))
  {
    f16x8 nv0 = *(const f16x8*)(rp);
    f16x8 nv1 = *(const f16x8*)(rp + RSTRIDE);
    f16x8 nv2 = *(const f16x8*)(rp + 2 * RSTRIDE);
    f16x8 nv3 = *(const f16x8*)(rp + 3 * RSTRIDE);
    mfma8(a00, a01, v00, v01, v02, v03, acc);
    a00 = a10; a01 = a11;
    v00 = nv0; v01 = nv1; v02 = nv2; v03 = nv3;
  }
  mfma8(a00, a01, v00, v01, v02, v03, acc);   // kc = NKC-1
}

__device__ __forceinline__ f16x4 relu_cvt4(float a0, float a1, float a2, float a3) {
  f16x2 lo = __builtin_bit_cast(f16x2, __builtin_amdgcn_cvt_pkrtz(a0, a1));
  f16x2 hi = __builtin_bit_cast(f16x2, __builtin_amdgcn_cvt_pkrtz(a2, a3));
  union { f16x4 v; f16x2 h[2]; } u;
  u.h[0] = lo; u.h[1] = hi;
  f16x4 z = {};
  return __builtin_elementwise_max(u.v, z);
}

// C/D 32x32: col(point) = lane&31, row(hidden) = (reg&3) + 8*(reg>>2) + 4*(lane>>5)
// Epilogue adds bias (acc + b) before relu, then f16x4 store.
__device__ __forceinline__ void store_epi(f32x16 acc[2][4],
                                          const float* __restrict__ bias,
                                          int wg, int p0, int h,
                                          _Float16* __restrict__ Hs) {
#pragma unroll
  for (int mt = 0; mt < 2; ++mt) {
    int hb = wg * 64 + mt * 32 + 4 * h;
#pragma unroll
    for (int g = 0; g < 4; ++g) {
      f32x4 q = *(const f32x4*)&bias[hb + 8 * g];
#pragma unroll
      for (int nt = 0; nt < 4; ++nt) {
        f16x4 o = relu_cvt4(acc[mt][nt][4 * g + 0] + q[0],
                            acc[mt][nt][4 * g + 1] + q[1],
                            acc[mt][nt][4 * g + 2] + q[2],
                            acc[mt][nt][4 * g + 3] + q[3]);
        *(f16x4*)&Hs[(nt * 32 + p0) * SH + hb + 8 * g] = o;
      }
    }
  }
}

__device__ __forceinline__ void emb_channel(_Float16* __restrict__ Erow,
                                            int c, float x) {
  _Float16 sv[6], cv[6];
  float fr = 1.f;
#pragma unroll
  for (int k = 0; k < 6; ++k) {
    float e = x * fr;
    sv[k] = (_Float16)__sinf(e);
    cv[k] = (_Float16)__cosf(e);
    fr *= 2.f;
  }
#pragma unroll
  for (int k = 0; k < 6; k += 2) {
    f16x2 s2 = {sv[k], sv[k + 1]};
    f16x2 c2 = {cv[k], cv[k + 1]};
    *(f16x2*)&Erow[6 * c + k]      = s2;
    *(f16x2*)&Erow[18 + 6 * c + k] = c2;
  }
  Erow[36 + c] = (_Float16)x;
}

// 256 threads = 4 waves: wave wg owns hidden slice [64wg, 64wg+64), all 128
// points. LDS: H 128xSH f16 (67584 B) + E 128xSE f16 (14336 B) = 81920 B
// -> 2 blocks/CU, 8 waves/CU (2/SIMD).
__global__ __launch_bounds__(256, 2)
void mlp_fused(const float* __restrict__ points,
               LayerPtrs P,
               const f16x8* __restrict__ wf,
               const float* __restrict__ wsdf,
               const float* __restrict__ bsdf,
               float* __restrict__ out) {
  __shared__ __align__(16) _Float16 Hs[128 * SH];   // 67584 B
  __shared__ __align__(16) _Float16 Es[128 * SE];   // 14336 B
  const int tid = threadIdx.x;
  const int blk = blockIdx.x;

  const int lane = tid & 63;
  const int wg   = tid >> 6;
  const int p0   = lane & 31;
  const int h    = lane >> 5;

  // frag(l, kc, mt) = wb[WOFF[l] + kc*512 + mt*64]; wave owns mtiles 2wg, 2wg+1
  const f16x8* wb = wf + wg * 128 + lane;

  // ---- embedding: 2 threads/point. part0 -> ch0,ch1; part1 -> ch2 + pad.
  // E cols: [sin(18) | cos(18) | xyz(3) | zeros 39..55]; row = point.
  {
    int p = tid & 127, part = tid >> 7;
    _Float16* Erow = &Es[p * SE];
    const float* pp = &points[(blk * 128 + p) * 3];
    if (part == 0) {
      emb_channel(Erow, 0, pp[0]);
      emb_channel(Erow, 1, pp[1]);
    } else {
      emb_channel(Erow, 2, pp[2]);
      Erow[39] = (_Float16)0.f;
      f16x4 z4 = {};
      *(f16x4*)&Erow[40] = z4;
      *(f16x4*)&Erow[44] = z4;
      *(f16x4*)&Erow[48] = z4;
      *(f16x4*)&Erow[52] = z4;
    }
  }
  __syncthreads();

  const char* hR = (const char*)Hs + (p0 * SH + 8 * h) * 2;
  const char* eR = (const char*)Es + (p0 * SE + 8 * h) * 2;

  f32x16 acc[2][4];

  // L0: read E, write H (disjoint -> no barrier between mm and store)
  mm<3, true, 32 * SE * 2>(wb, eR, acc);
  store_epi(acc, P.b[0], wg, p0, h, Hs);
  __syncthreads();

  const int WOFF[8] = {0, 1536, 9728, 17920, 26112, 35840, 44032, 52224};

  // L1..L3: in-place H
#pragma unroll
  for (int l = 1; l < 4; ++l) {
    mm<16, true, 32 * SH * 2>(wb + WOFF[l], hR, acc);
    __syncthreads();
    store_epi(acc, P.b[l], wg, p0, h, Hs);
    __syncthreads();
  }

  // L4: concat input = E (3 kc, zero-C) + H (16 kc, accumulate)
  {
    mm<3, true, 32 * SE * 2>(wb + 26112, eR, acc);
    mm<16, false, 32 * SH * 2>(wb + 27648, hR, acc);
    __syncthreads();
    store_epi(acc, P.b[4], wg, p0, h, Hs);
    __syncthreads();
  }

  // L5..L6
#pragma unroll
  for (int l = 5; l < 7; ++l) {
    mm<16, true, 32 * SH * 2>(wb + WOFF[l], hR, acc);
    __syncthreads();
    store_epi(acc, P.b[l], wg, p0, h, Hs);
    __syncthreads();
  }

  // L7 + SDF head: out[p] = sum_h relu(x7 + b7)[p][h] * wsdf[h] + bsdf
  mm<16, true, 32 * SH * 2>(wb + 52224, hR, acc);
  {
    float part[4] = {0.f, 0.f, 0.f, 0.f};
    const float* b7 = P.b[7];
#pragma unroll
    for (int mt = 0; mt < 2; ++mt) {
#pragma unroll
      for (int g = 0; g < 4; ++g) {
        int idx = wg * 64 + mt * 32 + 8 * g + 4 * h;
        f32x4 qb = *(const f32x4*)&b7[idx];
        f32x4 qw = *(const f32x4*)&wsdf[idx];
#pragma unroll
        for (int nt = 0; nt < 4; ++nt)
#pragma unroll
          for (int r = 0; r < 4; ++r)
            part[nt] += fmaxf(acc[mt][nt][4 * g + r] + qb[r], 0.f) * qw[r];
      }
    }
    // E space dead since L4 (block-wide barriers since) -> partial buffer
    // PB[8][128] floats (4 KB). PB writes touch only Es; L7 reads only Hs.
    float* PB = (float*)Es;
#pragma unroll
    for (int nt = 0; nt < 4; ++nt)
      PB[(wg * 2 + h) * 128 + nt * 32 + p0] = part[nt];
    __syncthreads();
    if (tid < 128) {
      float s = bsdf[0];
#pragma unroll
      for (int j = 0; j < 8; ++j) s += PB[j * 128 + tid];
      out[blk * 128 + tid] = s;
    }
  }
}

extern "C" void kernel_launch(void* const* d_in, const int* in_sizes, int n_in,
                              void* d_out, int out_size, void* d_ws, size_t ws_size,
                              hipStream_t stream) {
  const float* points = (const float*)d_in[0];
  LayerPtrs P;
  for (int i = 0; i < 8; ++i) {
    P.w[i] = (const float*)d_in[1 + 2 * i];
    P.b[i] = (const float*)d_in[2 + 2 * i];
  }
  const float* wsdf = (const float*)d_in[17];
  const float* bsdf = (const float*)d_in[18];
  f16x8* wf = (f16x8*)d_ws;   // needs 966656 B

  int N = in_sizes[0] / 3;    // 262144
  prep_weights<<<236, 256, 0, stream>>>(P, wf);
  mlp_fused<<<N / 128, 256, 0, stream>>>(points, P, wf, wsdf, bsdf, (float*)d_out);
}

// Round 7
// 296.235 us; speedup vs baseline: 1.5983x; 1.0114x over previous
//
#include <hip/hip_runtime.h>
#include <hip/hip_fp16.h>

typedef _Float16 f16x8 __attribute__((ext_vector_type(8)));
typedef _Float16 f16x4 __attribute__((ext_vector_type(4)));
typedef _Float16 f16x2 __attribute__((ext_vector_type(2)));
typedef float    f32x16 __attribute__((ext_vector_type(16)));
typedef float    f32x4 __attribute__((ext_vector_type(4)));

#define SH 264   // H row stride (f16): 528 B; 528 mod 128 = 16 -> banks spread
#define SE 56    // E row stride (f16): 112 B; 112 mod 128 = 112 -> banks spread

struct LayerPtrs {
  const float* w[8];
  const float* b[8];
};

// Weight fragments in d_ws, A-operand layout for mfma_f32_32x32x16_f16:
//   m = mtile*32 + (lane&31), k = kc*16 + (lane>>5)*8 + j ; value = W[k][m]
// index = WOFF[l] + (kc*8 + mtile)*64 + lane, element j.
__global__ void prep_weights(LayerPtrs P, f16x8* __restrict__ wf) {
  int gid = blockIdx.x * 256 + threadIdx.x;
  if (gid >= 60416) return;
  const int OFF[9] = {0,1536,9728,17920,26112,35840,44032,52224,60416};
  int l = 0;
  while (gid >= OFF[l+1]) ++l;
  int f = gid - OFF[l];
  int lane = f & 63;
  int t = f >> 6;
  int mtile = t & 7;
  int kc = t >> 3;
  int col = mtile * 32 + (lane & 31);
  int kb  = (lane >> 5) * 8;
  const float* w = P.w[l];
  f16x8 v;
#pragma unroll
  for (int j = 0; j < 8; ++j) {
    float x = 0.f;
    if (l == 4) {
      if (kc < 3) {
        int k = kc * 16 + kb + j;
        if (k < 39) x = w[k * 256 + col];
      } else {
        int k = (kc - 3) * 16 + kb + j;
        x = w[(39 + k) * 256 + col];
      }
    } else if (l == 0) {
      int k = kc * 16 + kb + j;
      if (k < 39) x = w[k * 256 + col];
    } else {
      int k = kc * 16 + kb + j;
      x = w[k * 256 + col];
    }
    v[j] = (_Float16)x;
  }
  wf[gid] = v;
}

#define MFMA __builtin_amdgcn_mfma_f32_32x32x16_f16

// A-pair load via inline asm: WE own the loads so WE own the waits.
// (Round-6 lesson: compiler-tracked rotated loads get conservative vmcnt
// drains -> full L2 latency exposed per kc -> MfmaUtil pinned ~50%.)
// mt stride = 64 f16x8 = 1024 B -> second load via offset imm.
__device__ __forceinline__ void aload2(f16x8& d0, f16x8& d1, const f16x8* p) {
  asm volatile("global_load_dwordx4 %0, %2, off\n\t"
               "global_load_dwordx4 %1, %2, off offset:1024"
               : "=&v"(d0), "=&v"(d1)
               : "v"(p));
}

__device__ __forceinline__ void mfma8(f16x8 a0, f16x8 a1,
                                      f16x8 v0, f16x8 v1, f16x8 v2, f16x8 v3,
                                      f32x16 acc[2][4]) {
  acc[0][0] = MFMA(a0, v0, acc[0][0], 0, 0, 0);
  acc[0][1] = MFMA(a0, v1, acc[0][1], 0, 0, 0);
  acc[0][2] = MFMA(a0, v2, acc[0][2], 0, 0, 0);
  acc[0][3] = MFMA(a0, v3, acc[0][3], 0, 0, 0);
  acc[1][0] = MFMA(a1, v0, acc[1][0], 0, 0, 0);
  acc[1][1] = MFMA(a1, v1, acc[1][1], 0, 0, 0);
  acc[1][2] = MFMA(a1, v2, acc[1][2], 0, 0, 0);
  acc[1][3] = MFMA(a1, v3, acc[1][3], 0, 0, 0);
}

__device__ __forceinline__ void mfma8_z(f16x8 a0, f16x8 a1,
                                        f16x8 v0, f16x8 v1, f16x8 v2, f16x8 v3,
                                        f32x16 acc[2][4]) {
  const f32x16 z = {};
  acc[0][0] = MFMA(a0, v0, z, 0, 0, 0);
  acc[0][1] = MFMA(a0, v1, z, 0, 0, 0);
  acc[0][2] = MFMA(a0, v2, z, 0, 0, 0);
  acc[0][3] = MFMA(a0, v3, z, 0, 0, 0);
  acc[1][0] = MFMA(a1, v0, z, 0, 0, 0);
  acc[1][1] = MFMA(a1, v1, z, 0, 0, 0);
  acc[1][2] = MFMA(a1, v2, z, 0, 0, 0);
  acc[1][3] = MFMA(a1, v3, z, 0, 0, 0);
}

// Wave = 64 hidden (2 mt) x 128 points (4 nt): 8 MFMA per kc, per-wave
// DISTINCT weight slice. A: asm loads, rotation distance-2 (pair kc+2
// issued at kc), counted waits:
//   steady (kc+2<NKC): 4 newer loads in flight -> s_waitcnt vmcnt(4)
//   kc==NKC-2: 2 newer -> vmcnt(2);  kc==NKC-1: vmcnt(0)
// sched_barrier(0) after the wait pins the MFMAs behind it (rule #18).
// V (LDS) distance-1 via compiler ds_read (lgkmcnt auto-handled).
// FIRST: kc0 uses zero C operand (bias added in epilogue).
template<int NKC, bool FIRST, int RSTRIDE>
__device__ __forceinline__ void mm(const f16x8* __restrict__ wb,
                                   const char* __restrict__ r0,
                                   f32x16 acc[2][4]) {
  f16x8 a00, a01, a10, a11;
  aload2(a00, a01, wb);                        // pair 0
  if (NKC > 1) aload2(a10, a11, wb + 512);     // pair 1
  f16x8 v0 = *(const f16x8*)(r0);
  f16x8 v1 = *(const f16x8*)(r0 + RSTRIDE);
  f16x8 v2 = *(const f16x8*)(r0 + 2 * RSTRIDE);
  f16x8 v3 = *(const f16x8*)(r0 + 3 * RSTRIDE);
#pragma unroll
  for (int kc = 0; kc < NKC; ++kc) {
    f16x8 na0, na1, nv0, nv1, nv2, nv3;
    if (kc + 2 < NKC) aload2(na0, na1, wb + (kc + 2) * 512);
    if (kc + 1 < NKC) {
      const char* rp = r0 + 32 * (kc + 1);
      nv0 = *(const f16x8*)(rp);
      nv1 = *(const f16x8*)(rp + RSTRIDE);
      nv2 = *(const f16x8*)(rp + 2 * RSTRIDE);
      nv3 = *(const f16x8*)(rp + 3 * RSTRIDE);
    }
    if (kc + 2 < NKC)      asm volatile("s_waitcnt vmcnt(4)");
    else if (kc + 1 < NKC) asm volatile("s_waitcnt vmcnt(2)");
    else                   asm volatile("s_waitcnt vmcnt(0)");
    __builtin_amdgcn_sched_barrier(0);
    if (FIRST && kc == 0) mfma8_z(a00, a01, v0, v1, v2, v3, acc);
    else                  mfma8 (a00, a01, v0, v1, v2, v3, acc);
    if (kc + 1 < NKC) {
      a00 = a10; a01 = a11;
      v0 = nv0; v1 = nv1; v2 = nv2; v3 = nv3;
    }
    if (kc + 2 < NKC) { a10 = na0; a11 = na1; }
  }
}

__device__ __forceinline__ f16x4 relu_cvt4(float a0, float a1, float a2, float a3) {
  f16x2 lo = __builtin_bit_cast(f16x2, __builtin_amdgcn_cvt_pkrtz(a0, a1));
  f16x2 hi = __builtin_bit_cast(f16x2, __builtin_amdgcn_cvt_pkrtz(a2, a3));
  union { f16x4 v; f16x2 h[2]; } u;
  u.h[0] = lo; u.h[1] = hi;
  f16x4 z = {};
  return __builtin_elementwise_max(u.v, z);
}

// C/D 32x32: col(point) = lane&31, row(hidden) = (reg&3) + 8*(reg>>2) + 4*(lane>>5)
// Epilogue adds bias (acc + b) before relu, then f16x4 store.
__device__ __forceinline__ void store_epi(f32x16 acc[2][4],
                                          const float* __restrict__ bias,
                                          int wg, int p0, int h,
                                          _Float16* __restrict__ Hs) {
#pragma unroll
  for (int mt = 0; mt < 2; ++mt) {
    int hb = wg * 64 + mt * 32 + 4 * h;
#pragma unroll
    for (int g = 0; g < 4; ++g) {
      f32x4 q = *(const f32x4*)&bias[hb + 8 * g];
#pragma unroll
      for (int nt = 0; nt < 4; ++nt) {
        f16x4 o = relu_cvt4(acc[mt][nt][4 * g + 0] + q[0],
                            acc[mt][nt][4 * g + 1] + q[1],
                            acc[mt][nt][4 * g + 2] + q[2],
                            acc[mt][nt][4 * g + 3] + q[3]);
        *(f16x4*)&Hs[(nt * 32 + p0) * SH + hb + 8 * g] = o;
      }
    }
  }
}

__device__ __forceinline__ void emb_channel(_Float16* __restrict__ Erow,
                                            int c, float x) {
  _Float16 sv[6], cv[6];
  float fr = 1.f;
#pragma unroll
  for (int k = 0; k < 6; ++k) {
    float e = x * fr;
    sv[k] = (_Float16)__sinf(e);
    cv[k] = (_Float16)__cosf(e);
    fr *= 2.f;
  }
#pragma unroll
  for (int k = 0; k < 6; k += 2) {
    f16x2 s2 = {sv[k], sv[k + 1]};
    f16x2 c2 = {cv[k], cv[k + 1]};
    *(f16x2*)&Erow[6 * c + k]      = s2;
    *(f16x2*)&Erow[18 + 6 * c + k] = c2;
  }
  Erow[36 + c] = (_Float16)x;
}

// 256 threads = 4 waves: wave wg owns hidden slice [64wg, 64wg+64), all 128
// points. LDS: H 128xSH f16 (67584 B) + E 128xSE f16 (14336 B) = 81920 B
// -> 2 blocks/CU, 8 waves/CU (2/SIMD).
__global__ __launch_bounds__(256, 2)
void mlp_fused(const float* __restrict__ points,
               LayerPtrs P,
               const f16x8* __restrict__ wf,
               const float* __restrict__ wsdf,
               const float* __restrict__ bsdf,
               float* __restrict__ out) {
  __shared__ __align__(16) _Float16 Hs[128 * SH];   // 67584 B
  __shared__ __align__(16) _Float16 Es[128 * SE];   // 14336 B
  const int tid = threadIdx.x;
  const int blk = blockIdx.x;

  const int lane = tid & 63;
  const int wg   = tid >> 6;
  const int p0   = lane & 31;
  const int h    = lane >> 5;

  // frag(l, kc, mt) = wb[WOFF[l] + kc*512 + mt*64]; wave owns mtiles 2wg, 2wg+1
  const f16x8* wb = wf + wg * 128 + lane;

  // ---- embedding: 2 threads/point. part0 -> ch0,ch1; part1 -> ch2 + pad.
  // E cols: [sin(18) | cos(18) | xyz(3) | zeros 39..55]; row = point.
  {
    int p = tid & 127, part = tid >> 7;
    _Float16* Erow = &Es[p * SE];
    const float* pp = &points[(blk * 128 + p) * 3];
    if (part == 0) {
      emb_channel(Erow, 0, pp[0]);
      emb_channel(Erow, 1, pp[1]);
    } else {
      emb_channel(Erow, 2, pp[2]);
      Erow[39] = (_Float16)0.f;
      f16x4 z4 = {};
      *(f16x4*)&Erow[40] = z4;
      *(f16x4*)&Erow[44] = z4;
      *(f16x4*)&Erow[48] = z4;
      *(f16x4*)&Erow[52] = z4;
    }
  }
  __syncthreads();

  const char* hR = (const char*)Hs + (p0 * SH + 8 * h) * 2;
  const char* eR = (const char*)Es + (p0 * SE + 8 * h) * 2;

  f32x16 acc[2][4];

  // L0: read E, write H (disjoint -> no barrier between mm and store)
  mm<3, true, 32 * SE * 2>(wb, eR, acc);
  store_epi(acc, P.b[0], wg, p0, h, Hs);
  __syncthreads();

  const int WOFF[8] = {0, 1536, 9728, 17920, 26112, 35840, 44032, 52224};

  // L1..L3: in-place H
#pragma unroll
  for (int l = 1; l < 4; ++l) {
    mm<16, true, 32 * SH * 2>(wb + WOFF[l], hR, acc);
    __syncthreads();
    store_epi(acc, P.b[l], wg, p0, h, Hs);
    __syncthreads();
  }

  // L4: concat input = E (3 kc, zero-C) + H (16 kc, accumulate)
  {
    mm<3, true, 32 * SE * 2>(wb + 26112, eR, acc);
    mm<16, false, 32 * SH * 2>(wb + 27648, hR, acc);
    __syncthreads();
    store_epi(acc, P.b[4], wg, p0, h, Hs);
    __syncthreads();
  }

  // L5..L6
#pragma unroll
  for (int l = 5; l < 7; ++l) {
    mm<16, true, 32 * SH * 2>(wb + WOFF[l], hR, acc);
    __syncthreads();
    store_epi(acc, P.b[l], wg, p0, h, Hs);
    __syncthreads();
  }

  // L7 + SDF head: out[p] = sum_h relu(x7 + b7)[p][h] * wsdf[h] + bsdf
  mm<16, true, 32 * SH * 2>(wb + 52224, hR, acc);
  {
    float part[4] = {0.f, 0.f, 0.f, 0.f};
    const float* b7 = P.b[7];
#pragma unroll
    for (int mt = 0; mt < 2; ++mt) {
#pragma unroll
      for (int g = 0; g < 4; ++g) {
        int idx = wg * 64 + mt * 32 + 8 * g + 4 * h;
        f32x4 qb = *(const f32x4*)&b7[idx];
        f32x4 qw = *(const f32x4*)&wsdf[idx];
#pragma unroll
        for (int nt = 0; nt < 4; ++nt)
#pragma unroll
          for (int r = 0; r < 4; ++r)
            part[nt] += fmaxf(acc[mt][nt][4 * g + r] + qb[r], 0.f) * qw[r];
      }
    }
    // E space dead since L4 (block-wide barriers since) -> partial buffer
    // PB[8][128] floats (4 KB). PB writes touch only Es; L7 reads only Hs.
    float* PB = (float*)Es;
#pragma unroll
    for (int nt = 0; nt < 4; ++nt)
      PB[(wg * 2 + h) * 128 + nt * 32 + p0] = part[nt];
    __syncthreads();
    if (tid < 128) {
      float s = bsdf[0];
#pragma unroll
      for (int j = 0; j < 8; ++j) s += PB[j * 128 + tid];
      out[blk * 128 + tid] = s;
    }
  }
}

extern "C" void kernel_launch(void* const* d_in, const int* in_sizes, int n_in,
                              void* d_out, int out_size, void* d_ws, size_t ws_size,
                              hipStream_t stream) {
  const float* points = (const float*)d_in[0];
  LayerPtrs P;
  for (int i = 0; i < 8; ++i) {
    P.w[i] = (const float*)d_in[1 + 2 * i];
    P.b[i] = (const float*)d_in[2 + 2 * i];
  }
  const float* wsdf = (const float*)d_in[17];
  const float* bsdf = (const float*)d_in[18];
  f16x8* wf = (f16x8*)d_ws;   // needs 966656 B

  int N = in_sizes[0] / 3;    // 262144
  prep_weights<<<236, 256, 0, stream>>>(P, wf);
  mlp_fused<<<N / 128, 256, 0, stream>>>(points, P, wf, wsdf, bsdf, (float*)d_out);
}